// Round 7
// baseline (165.379 us; speedup 1.0000x reference)
//
#include <hip/hip_runtime.h>
#include <hip/hip_bf16.h>

#define LEVEL 256
#define BLOCKS 8
// B=16, H=W=1024, bm=bn=128, tv = 16384/256*10 = 640

typedef float f32x4 __attribute__((ext_vector_type(4)));   // native vec for nontemporal builtins

// ---------------------------------------------------------------------------
// Kernel 1: per-image-block histogram -> clip -> cdf -> map table.
// Per-wave privatized histograms (4 x 256 int) kill inter-wave LDS-atomic
// contention. Stages pixels as uint8 so kernel 2 reads 16 MB instead of 64.
// grid = 1024, 256 threads. maps layout: float maps[16][8][8][256]
// ---------------------------------------------------------------------------
__global__ __launch_bounds__(256) void clahe_hist_kernel(const float* __restrict__ img,
                                                         float* __restrict__ maps,
                                                         unsigned char* __restrict__ u8img) {
    __shared__ int   hist[4][256];
    __shared__ float red[256];
    __shared__ float scan[256];
    __shared__ float s_me;

    const int t    = threadIdx.x;
    const int wave = t >> 6;
    const int bid  = blockIdx.x;           // 0..1023
    const int b    = bid >> 6;
    const int blk  = bid & 63;
    const int br   = blk >> 3;
    const int bc   = blk & 7;

    hist[0][t] = 0; hist[1][t] = 0; hist[2][t] = 0; hist[3][t] = 0;
    __syncthreads();

    const size_t base = (size_t)b * 1048576 + (size_t)(br * 128) * 1024 + (size_t)(bc * 128);
    const float* p = img + base;
    unsigned char* q8 = u8img + base;
    int* myhist = hist[wave];
#pragma unroll
    for (int it = 0; it < 16; ++it) {
        int idx = it * 256 + t;            // 0..4095
        int y   = idx >> 5;                // 0..127
        int x   = (idx & 31) * 4;          // 0..124
        const float* src = p + (size_t)y * 1024 + x;
        float4 v;
        v.x = __builtin_nontemporal_load(src + 0);   // floats never re-read
        v.y = __builtin_nontemporal_load(src + 1);
        v.z = __builtin_nontemporal_load(src + 2);
        v.w = __builtin_nontemporal_load(src + 3);
        int va = (int)v.x, vb = (int)v.y, vc = (int)v.z, vd = (int)v.w;
        atomicAdd(&myhist[va], 1);
        atomicAdd(&myhist[vb], 1);
        atomicAdd(&myhist[vc], 1);
        atomicAdd(&myhist[vd], 1);
        uchar4 pk;
        pk.x = (unsigned char)va; pk.y = (unsigned char)vb;
        pk.z = (unsigned char)vc; pk.w = (unsigned char)vd;
        *(uchar4*)(q8 + (size_t)y * 1024 + x) = pk;
    }
    __syncthreads();

    float h = (float)(hist[0][t] + hist[1][t] + hist[2][t] + hist[3][t]);

    // clip: tv=640, redistribute excess uniformly (integer-exact fp32)
    const float tv = 640.0f;
    red[t] = fmaxf(h - tv, 0.0f);
    __syncthreads();
    for (int off = 128; off > 0; off >>= 1) {
        if (t < off) red[t] += red[t + off];
        __syncthreads();
    }
    if (t == 0) s_me = red[0] * (1.0f / 256.0f);   // exact /2^8
    __syncthreads();
    const float me = s_me;
    float clip = floorf(((h >= tv) ? tv : h) + me);

    // inclusive scan (integer-valued -> exact any order)
    scan[t] = clip;
    __syncthreads();
    for (int off = 1; off < 256; off <<= 1) {
        float add = (t >= off) ? scan[t - off] : 0.0f;
        __syncthreads();
        scan[t] += add;
        __syncthreads();
    }
    float cdf = scan[t] * (255.0f / 16384.0f);     // exact 255/2^14
    maps[(size_t)bid * 256 + t] = (float)(((int)floorf(cdf)) & 255);
}

// ---------------------------------------------------------------------------
// Kernel 2: bilinear blend, INTEGER-EXACT formulation.
// The reference's fp32 blend is exactly N/16384 with
//   N = (128-b)*((128-a)*lu + a*lb) + b*((128-a)*ru + a*rb),
// a = x1*128, b = y1*128 (integers in [-64,127]); every fp32 intermediate is
// an exact multiple of 2^-14 below 2^24, so int math == reference bit-for-bit.
// trunc + floor-mod-256  ==  signed N/16384 (C trunc division) & 255.
// 64x64 tile/WG, 16 px/thread via one uint4 load; tbl = u8x4-packed corners
// -> single random-bank ds_read_b32 per pixel.
// grid = (16,16,16), 256 threads.
// ---------------------------------------------------------------------------
__global__ __launch_bounds__(256) void clahe_map_kernel(const unsigned char* __restrict__ img8,
                                                        const float* __restrict__ maps,
                                                        float* __restrict__ out) {
    __shared__ unsigned int tbl[256];   // packed {lu,lb,ru,rb}

    const int t  = threadIdx.x;
    const int bz = blockIdx.z;
    const int i0 = blockIdx.y * 64;
    const int j0 = blockIdx.x * 64;

    // r = trunc((i-64)/128), constant over a 64-aligned tile
    const int r  = (i0 >= 64) ? ((i0 - 64) >> 7) : 0;
    const int c  = (j0 >= 64) ? ((j0 - 64) >> 7) : 0;
    const int rp = min(r + 1, BLOCKS - 1);
    const int cp = min(c + 1, BLOCKS - 1);
    const bool rEdge = (r >= BLOCKS - 1);
    const bool cEdge = (c >= BLOCKS - 1);

    const float* mb = maps + (size_t)bz * 64 * 256;
    {
        unsigned lu = (unsigned)(int)mb[(r  * 8 + c ) * 256 + t];
        unsigned lb = (unsigned)(int)mb[(rp * 8 + c ) * 256 + t];
        unsigned ru = (unsigned)(int)mb[(r  * 8 + cp) * 256 + t];
        unsigned rb = (unsigned)(int)mb[(rp * 8 + cp) * 256 + t];
        tbl[t] = lu | (lb << 8) | (ru << 16) | (rb << 24);
    }
    __syncthreads();

    const int row   = t >> 2;          // 0..63
    const int col16 = (t & 3) * 16;    // 0,16,32,48
    const int i = i0 + row;
    const int j = j0 + col16;

    const int wa1 = rEdge ? 0 : (i - (r * 128 + 64));   // a in [-64,127]
    const int wa0 = 128 - wa1;
    const int b0  = cEdge ? 0 : (j - (c * 128 + 64));   // col weight at k=0
    const int bst = cEdge ? 0 : 1;

    const size_t off = (size_t)bz * 1048576 + (size_t)i * 1024 + j;
    const uint4 w = *(const uint4*)(img8 + off);
    const unsigned words[4] = { w.x, w.y, w.z, w.w };

    float o[16];
#pragma unroll
    for (int m = 0; m < 4; ++m) {
#pragma unroll
        for (int k = 0; k < 4; ++k) {
            const int pi = m * 4 + k;
            const int v  = (words[m] >> (k * 8)) & 255;
            const unsigned mv = tbl[v];
            const int lu = mv & 255u;
            const int lb = (mv >> 8) & 255u;
            const int ru = (mv >> 16) & 255u;
            const int rb = mv >> 24;
            const int bb = b0 + bst * pi;               // b in [-64,127]
            const int P  = __mul24(wa0, lu) + __mul24(wa1, lb);   // |P| <= 48960
            const int Q  = __mul24(wa0, ru) + __mul24(wa1, rb);
            const int N  = __mul24(128 - bb, P) + __mul24(bb, Q); // |N| < 2^24
            o[pi] = (float)((N / 16384) & 255);         // trunc-div == ref
        }
    }

    float* dst = out + off;
#pragma unroll
    for (int m = 0; m < 4; ++m) {
        f32x4 v4 = { o[m * 4 + 0], o[m * 4 + 1], o[m * 4 + 2], o[m * 4 + 3] };
        __builtin_nontemporal_store(v4, (f32x4*)(dst + m * 4));
    }
}

extern "C" void kernel_launch(void* const* d_in, const int* in_sizes, int n_in,
                              void* d_out, int out_size, void* d_ws, size_t ws_size,
                              hipStream_t stream) {
    const float* img = (const float*)d_in[0];
    float* out  = (float*)d_out;
    float* maps = (float*)d_ws;                                                // 1 MB
    unsigned char* u8img = (unsigned char*)d_ws + (size_t)1024 * 256 * 4;      // 16 MB

    clahe_hist_kernel<<<dim3(1024), dim3(256), 0, stream>>>(img, maps, u8img);
    clahe_map_kernel<<<dim3(16, 16, 16), dim3(256), 0, stream>>>(u8img, maps, out);
}